// Round 11
// baseline (256.738 us; speedup 1.0000x reference)
//
#include <hip/hip_runtime.h>
#include <hip/hip_bf16.h>

// WindowAttention (Swin) single fused per-window kernel for MI355X, round 11.
// LDS diet: X read direct from global (roll folded into row pointers), Q kept in
// registers via shfl-dance -> LDS = K + V^T = 51.2KB -> 3 blocks/CU.
// bf16 MFMA, f32 accum. Fragment layout (gfx950, verified r2-r10):
//   A (16x32): lane l holds A[l&15][8*(l>>4)+j]   B (32x16): lane l holds B[8*(l>>4)+j][l&15]
//   C/D: lane l reg r -> C[4*(l>>4)+r][l&15]
// Attention trick (r6): S^T = K·Q^T with K-tile T loading rows
//   kt = 8*(l15>>2) + 4*(T&1) + 32*(T>>1) + (l15&3)
// -> lane (l15,g) holds P[q=l15][kt=g*8+...]: softmax = local sum + 2 shfl_xor,
//    and the packed quads are exactly the PV A-frag slices.

typedef __bf16 bf16x8 __attribute__((ext_vector_type(8)));
typedef __bf16 bf16x4 __attribute__((ext_vector_type(4)));
typedef float f32x4 __attribute__((ext_vector_type(4)));
using bf = __bf16;

#define MFMA16(a, b, c) __builtin_amdgcn_mfma_f32_16x16x32_bf16((a), (b), (c), 0, 0, 0)

static constexpr float kNEG = -1000000000.0f;
static constexpr float kScale = 0.17677669529663687f;  // 32^-0.5

// workspace (bytes): read-only prep products
static constexpr size_t OFF_WQKVT = 0;        // bf16 [576][192]
static constexpr size_t OFF_WOUTT = 221184;   // bf16 [192][192]
static constexpr size_t OFF_TBLBF = 294912;   // bf16 [4][49][68]

// LDS: K [6][49][40] @0 (23520B, aliased by O [49][200] 19600B after QK^T barrier),
//      V^T [6][32][72] @23520 (27648B). Total 51168B -> 3 blocks/CU.
static constexpr int KO_OFF  = 0;
static constexpr int V_OFF   = 23520;
static constexpr int LDS_B   = 51168;
static constexpr int KSTR    = 40;
static constexpr int VSTR    = 72;
static constexpr int OSTR    = 200;

__device__ __forceinline__ unsigned pack2(float a, float b) {
  union { bf h[2]; unsigned u; } cv;
  cv.h[0] = (bf)a; cv.h[1] = (bf)b;
  return cv.u;
}

// load 8 consecutive f32 -> bf16x8
__device__ __forceinline__ bf16x8 ldcvt(const float* p) {
  bf16x8 v;
#pragma unroll
  for (int j = 0; j < 8; ++j) v[j] = (bf)p[j];
  return v;
}

// ---------------- K0: weight transposes + bf16 bias/mask tables ----------------
__global__ void prep_kernel(const float* __restrict__ wqkv, const float* __restrict__ wout,
                            const float* __restrict__ pos, char* __restrict__ ws) {
  bf* wqkvT = (bf*)(ws + OFF_WQKVT);
  bf* woutT = (bf*)(ws + OFF_WOUTT);
  bf* tblbf = (bf*)(ws + OFF_TBLBF);
  int tid = blockIdx.x * blockDim.x + threadIdx.x;
  int nthr = gridDim.x * blockDim.x;
  for (int i = tid; i < 192 * 576; i += nthr) {
    int k = i / 576, n = i % 576;
    wqkvT[n * 192 + k] = (bf)wqkv[i];
  }
  for (int i = tid; i < 192 * 192; i += nthr) {
    int k = i / 192, n = i % 192;
    woutT[n * 192 + k] = (bf)wout[i];
  }
  for (int i = tid; i < 4 * 49 * 68; i += nthr) {
    int type = i / (49 * 68), rem = i % (49 * 68), r = rem / 68, c = rem % 68;
    float v = 0.0f;
    if (c < 64) {
      if (c < 49) {
        int ix = r / 7, iy = r % 7, jx = c / 7, jy = c % 7;
        v = pos[(jx - ix + 6) * 13 + (jy - iy + 6)];
        if ((type & 1) && ((r >= 28) != (c >= 28))) v += kNEG;  // ul mask
        if ((type & 2) && ((iy >= 4) != (jy >= 4))) v += kNEG;  // lr mask
      } else {
        v = kNEG;  // pad cols -> P==0
      }
    }
    tblbf[i] = (bf)v;
  }
}

// ---------------- fused: 1 block = 1 window, 512 thr (8 waves) ----------------
__global__ __launch_bounds__(512, 6) void fused_kernel(const float* __restrict__ x,
                                                       const float* __restrict__ bout,
                                                       const char* __restrict__ ws,
                                                       float* __restrict__ out) {
  __shared__ __align__(16) char smem[LDS_B];
  bf* Kl = (bf*)(smem + KO_OFF);  // [6][49][40]
  bf* Ol = (bf*)(smem + KO_OFF);  // [49][200] (alias, after QK^T barrier)
  bf* Vl = (bf*)(smem + V_OFF);   // [6][32][72] (V^T: [head][d][t])

  const bf* wqkvT = (const bf*)(ws + OFF_WQKVT);
  const bf* woutT = (const bf*)(ws + OFF_WOUTT);

  int bw = blockIdx.x;
  int b = bw >> 6, win = bw & 63;
  int wh = win >> 3, wwi = win & 7;
  int type = ((wh == 7) ? 1 : 0) | ((wwi == 7) ? 2 : 0);
  const bf* Tb = (const bf*)(ws + OFF_TBLBF) + type * 49 * 68;

  int tid = threadIdx.x;
  int wave = tid >> 6, lane = tid & 63;
  int l15 = lane & 15, g = lane >> 4;

  // rolled x row pointer for token t (clamped to 48; dups handled downstream)
  auto rowptr = [&](int t) -> const float* {
    if (t > 48) t = 48;
    int tr = t / 7, tc = t % 7;
    int h = wh * 7 + tr + 3; if (h >= 56) h -= 56;
    int w = wwi * 7 + tc + 3; if (w >= 56) w -= 56;
    return x + (((size_t)b * 56 + h) * 56 + w) * 192;
  };

  int mrow = wave >> 2, ncol = wave & 3;   // phase-1a split
  int mq = wave & 3, hbase = wave >> 2;    // items: (head = hbase+2i, q-tile mq)
  const float* xr0 = rowptr(mrow * 32 + l15);
  const float* xr1 = rowptr(mrow * 32 + 16 + l15);
  const float* xrq = rowptr(mq * 16 + l15);

  // ---- phase 1a: K columns (ncol 0,1 -> swapped C^T) / V columns (ncol 2,3 -> normal) ----
  {
    bool isK = (ncol < 2);
    int nbase = 192 + ncol * 96;
    f32x4 acc[2][6] = {};
#pragma unroll
    for (int ks = 0; ks < 6; ++ks) {
      bf16x8 xf0 = ldcvt(xr0 + ks * 32 + g * 8);
      bf16x8 xf1 = ldcvt(xr1 + ks * 32 + g * 8);
#pragma unroll
      for (int nt = 0; nt < 6; ++nt) {
        bf16x8 wf = *(const bf16x8*)(wqkvT + (size_t)(nbase + nt * 16 + l15) * 192 + ks * 32 + g * 8);
        if (isK) {
          acc[0][nt] = MFMA16(wf, xf0, acc[0][nt]);   // C^T[n][t]
          acc[1][nt] = MFMA16(wf, xf1, acc[1][nt]);
        } else {
          acc[0][nt] = MFMA16(xf0, wf, acc[0][nt]);   // C[t][n]
          acc[1][nt] = MFMA16(xf1, wf, acc[1][nt]);
        }
      }
    }
    if (isK) {
#pragma unroll
      for (int nt = 0; nt < 6; ++nt) {
        int dg = ncol * 96 + nt * 16 + 4 * g;   // 0..191, 4-aligned, within one head
        int head = dg >> 5, d = dg & 31;
#pragma unroll
        for (int mt = 0; mt < 2; ++mt) {
          int t = mrow * 32 + mt * 16 + l15;
          if (t < 49) {
            uint2 pk;
            pk.x = pack2(acc[mt][nt][0], acc[mt][nt][1]);
            pk.y = pack2(acc[mt][nt][2], acc[mt][nt][3]);
            *(uint2*)(Kl + (head * 49 + t) * KSTR + d) = pk;
          }
        }
      }
    } else {
#pragma unroll
      for (int nt = 0; nt < 6; ++nt) {
        int dg = (ncol - 2) * 96 + nt * 16 + l15;
        int head = dg >> 5, d = dg & 31;
#pragma unroll
        for (int mt = 0; mt < 2; ++mt) {
          int t0 = mrow * 32 + mt * 16 + 4 * g;   // up to 60; t>=49 dups killed by P==0
          uint2 pk;
          pk.x = pack2(acc[mt][nt][0], acc[mt][nt][1]);
          pk.y = pack2(acc[mt][nt][2], acc[mt][nt][3]);
          *(uint2*)(Vl + (head * 32 + d) * VSTR + t0) = pk;
        }
      }
    }
  }

  // ---- phase 1b: Q for this wave's 3 items -> registers (swapped C^T + shfl dance) ----
  bf16x8 qf[3];
  {
    f32x4 qa[3][2] = {};
#pragma unroll
    for (int ks = 0; ks < 6; ++ks) {
      bf16x8 xq = ldcvt(xrq + ks * 32 + g * 8);
#pragma unroll
      for (int i = 0; i < 3; ++i) {
        int hi = hbase + 2 * i;
#pragma unroll
        for (int nt = 0; nt < 2; ++nt) {
          bf16x8 wf = *(const bf16x8*)(wqkvT + (size_t)(hi * 32 + nt * 16 + l15) * 192 + ks * 32 + g * 8);
          qa[i][nt] = MFMA16(wf, xq, qa[i][nt]);
        }
      }
    }
    // dance: C^T gives lane (l15,g') d=nt*16+4g'+r at q=l15; B-frag wants d=8g..8g+7 at q=l15.
    int srcA = l15 + 32 * (g & 1);
    int srcB = srcA + 16;
    bool hiT = (g >> 1) != 0;
#pragma unroll
    for (int i = 0; i < 3; ++i) {
      unsigned p00 = pack2(qa[i][0][0], qa[i][0][1]);
      unsigned p01 = pack2(qa[i][0][2], qa[i][0][3]);
      unsigned p10 = pack2(qa[i][1][0], qa[i][1][1]);
      unsigned p11 = pack2(qa[i][1][2], qa[i][1][3]);
      unsigned a0 = __shfl(p00, srcA), b0 = __shfl(p10, srcA);
      unsigned a1 = __shfl(p01, srcA), b1 = __shfl(p11, srcA);
      unsigned a2 = __shfl(p00, srcB), b2 = __shfl(p10, srcB);
      unsigned a3 = __shfl(p01, srcB), b3 = __shfl(p11, srcB);
      union { unsigned u[4]; bf16x8 v; } q;
      q.u[0] = hiT ? b0 : a0;
      q.u[1] = hiT ? b1 : a1;
      q.u[2] = hiT ? b2 : a2;
      q.u[3] = hiT ? b3 : a3;
      qf[i] = q.v;
    }
  }
  __syncthreads();  // K,V visible

  // ---- phase 3a: S^T = K·Q^T (perm tiles), bias (global), exp, lane-local softmax ----
  unsigned pp[3][4][2];
  int qq = mq * 16 + l15;
  int qc = qq > 48 ? 48 : qq;
#pragma unroll
  for (int i = 0; i < 3; ++i) {
    int hi = hbase + 2 * i;
    const bf* Kh = Kl + hi * 49 * KSTR;
    f32x4 sa[4];
#pragma unroll
    for (int T = 0; T < 4; ++T) {
      int kt = ((l15 >> 2) << 3) + ((T & 1) << 2) + ((T >> 1) << 5) + (l15 & 3);
      int ktc = kt > 48 ? 48 : kt;  // dup; killed by NEG bias col
      bf16x8 kf = *(const bf16x8*)(Kh + ktc * KSTR + g * 8);
      f32x4 z = {};
      sa[T] = MFMA16(kf, qf[i], z);
    }
    float e[4][4];
    float lsum = 0.0f;
#pragma unroll
    for (int T = 0; T < 4; ++T) {
      int cb = (g << 3) + ((T & 1) << 2) + ((T >> 1) << 5);
      bf16x4 bias = *(const bf16x4*)(Tb + qc * 68 + cb);
#pragma unroll
      for (int r = 0; r < 4; ++r) {
        float ev = __expf(sa[T][r] * kScale + (float)bias[r]);
        e[T][r] = ev;
        lsum += ev;
      }
    }
    lsum += __shfl_xor(lsum, 16);
    lsum += __shfl_xor(lsum, 32);
    float rinv = 1.0f / lsum;
#pragma unroll
    for (int T = 0; T < 4; ++T) {
      pp[i][T][0] = pack2(e[T][0] * rinv, e[T][1] * rinv);
      pp[i][T][1] = pack2(e[T][2] * rinv, e[T][3] * rinv);
    }
  }
  __syncthreads();  // all K reads done; K region -> O

  // ---- phase 3b: O = P·V (A-frags from pp regs), O -> LDS (alias of K) ----
#pragma unroll
  for (int i = 0; i < 3; ++i) {
    int hi = hbase + 2 * i;
    const bf* Vh = Vl + hi * 32 * VSTR;
    f32x4 o0 = {}, o1 = {};
#pragma unroll
    for (int ks = 0; ks < 2; ++ks) {
      union { unsigned u[4]; bf16x8 v; } af;
      af.u[0] = pp[i][2 * ks][0];
      af.u[1] = pp[i][2 * ks][1];
      af.u[2] = pp[i][2 * ks + 1][0];
      af.u[3] = pp[i][2 * ks + 1][1];
      bf16x8 v0 = *(const bf16x8*)(Vh + l15 * VSTR + ks * 32 + g * 8);
      bf16x8 v1 = *(const bf16x8*)(Vh + (16 + l15) * VSTR + ks * 32 + g * 8);
      o0 = MFMA16(af.v, v0, o0);
      o1 = MFMA16(af.v, v1, o1);
    }
#pragma unroll
    for (int r = 0; r < 4; ++r) {
      int orow = mq * 16 + 4 * g + r;
      if (orow < 49) {
        Ol[orow * OSTR + hi * 32 + l15]      = (bf)o0[r];
        Ol[orow * OSTR + hi * 32 + 16 + l15] = (bf)o1[r];
      }
    }
  }
  __syncthreads();  // O complete

  // ---- phase 4: proj (swapped C^T), float4 stores with inverse roll ----
  {
    int mw = wave >> 1, th = wave & 1;
    f32x4 pa[3][2] = {};
#pragma unroll
    for (int ks = 0; ks < 6; ++ks) {
      bf16x8 of[2];
#pragma unroll
      for (int mt = 0; mt < 2; ++mt) {
        int t = th * 32 + mt * 16 + l15; if (t > 48) t = 48;
        of[mt] = *(const bf16x8*)(Ol + t * OSTR + ks * 32 + g * 8);
      }
#pragma unroll
      for (int nt = 0; nt < 3; ++nt) {
        bf16x8 wf = *(const bf16x8*)(woutT + (size_t)(mw * 48 + nt * 16 + l15) * 192 + ks * 32 + g * 8);
#pragma unroll
        for (int mt = 0; mt < 2; ++mt) pa[nt][mt] = MFMA16(wf, of[mt], pa[nt][mt]);
      }
    }
#pragma unroll
    for (int nt = 0; nt < 3; ++nt) {
      int col0 = mw * 48 + nt * 16 + 4 * g;
      f32x4 bv = *(const f32x4*)(bout + col0);
#pragma unroll
      for (int mt = 0; mt < 2; ++mt) {
        int t = th * 32 + mt * 16 + l15;
        if (t < 49) {
          int tr = t / 7, tc = t % 7;
          int h = wh * 7 + tr + 3; if (h >= 56) h -= 56;
          int w2 = wwi * 7 + tc + 3; if (w2 >= 56) w2 -= 56;
          f32x4 vv = pa[nt][mt] + bv;
          *(f32x4*)(out + (((size_t)b * 56 + h) * 56 + w2) * 192 + col0) = vv;
        }
      }
    }
  }
}

extern "C" void kernel_launch(void* const* d_in, const int* in_sizes, int n_in,
                              void* d_out, int out_size, void* d_ws, size_t ws_size,
                              hipStream_t stream) {
  const float* x = (const float*)d_in[0];
  const float* wqkv = (const float*)d_in[1];
  const float* wout = (const float*)d_in[2];
  const float* bout = (const float*)d_in[3];
  const float* pos = (const float*)d_in[4];
  char* ws = (char*)d_ws;

  hipLaunchKernelGGL(prep_kernel, dim3(128), dim3(256), 0, stream, wqkv, wout, pos, ws);
  hipLaunchKernelGGL(fused_kernel, dim3(2048), dim3(512), 0, stream,
                     x, bout, (const char*)ws, (float*)d_out);
}